// Round 1
// baseline (8325.697 us; speedup 1.0000x reference)
//
#include <hip/hip_runtime.h>
#include <math.h>

// Problem constants
#define TT   240
#define BBATCH 64
#define DDIM 7056
#define NENC 512
#define MHID 256
#define G3   768
#define WRMC 40
#define KWIN 8
#define TOUTC 192
#define RROWS (TOUTC*BBATCH)   // 12288
#define NSTEPS (WRMC + TOUTC)  // 232

// ws layout (float offsets)
#define OFF_GI    ((size_t)0)                        // 240*64*768 = 11796480
#define OFF_Z     ((size_t)11796480)                 // 7864320 (phase 1 only)
#define OFF_HOPEN OFF_Z                              // 3145728 (reuse after scan)
#define OFF_R1    (OFF_Z + (size_t)3145728)          // 3145728
#define OFF_BTS   (OFF_Z + (size_t)7864320)          // 3276800
#define OFF_GTAB  (OFF_BTS + (size_t)3276800)        // 13824
#define OFF_GBH   OFF_GI                             // reuse gi space for open gh

__device__ __forceinline__ float sigmf(float x) { return 1.0f / (1.0f + expf(-x)); }

// C[M,N] = A[M,K] @ W[N,K]^T + bias (optional relu, optional strided out scatter)
// Tiles: 128x128, BK=16, 256 threads, 8x8 per thread.
__global__ __launch_bounds__(256) void gemm_tn(
    const float* __restrict__ A, const float* __restrict__ W,
    const float* __restrict__ bias, float* __restrict__ C,
    int Mrows, int Ncols, int Kdim, int relu, int outk)
{
  __shared__ float As[16][132];
  __shared__ float Bs[16][132];
  const int tid = threadIdx.x;
  const int bx = blockIdx.x, by = blockIdx.y;
  const int tx = tid & 15, ty = tid >> 4;
  const int lrow = tid >> 2;
  const int lk = (tid & 3) << 2;

  const float* Ab = A + (size_t)by * 128 * Kdim;
  const float* Wb = W + (size_t)bx * 128 * Kdim;

  float c[8][8];
#pragma unroll
  for (int i = 0; i < 8; ++i)
#pragma unroll
    for (int j = 0; j < 8; ++j) c[i][j] = 0.f;

  for (int k0 = 0; k0 < Kdim; k0 += 16) {
    const float4 a0 = *(const float4*)(Ab + (size_t)lrow * Kdim + k0 + lk);
    const float4 a1 = *(const float4*)(Ab + (size_t)(lrow + 64) * Kdim + k0 + lk);
    const float4 b0 = *(const float4*)(Wb + (size_t)lrow * Kdim + k0 + lk);
    const float4 b1 = *(const float4*)(Wb + (size_t)(lrow + 64) * Kdim + k0 + lk);
    __syncthreads();
    As[lk + 0][lrow] = a0.x; As[lk + 1][lrow] = a0.y; As[lk + 2][lrow] = a0.z; As[lk + 3][lrow] = a0.w;
    As[lk + 0][lrow + 64] = a1.x; As[lk + 1][lrow + 64] = a1.y; As[lk + 2][lrow + 64] = a1.z; As[lk + 3][lrow + 64] = a1.w;
    Bs[lk + 0][lrow] = b0.x; Bs[lk + 1][lrow] = b0.y; Bs[lk + 2][lrow] = b0.z; Bs[lk + 3][lrow] = b0.w;
    Bs[lk + 0][lrow + 64] = b1.x; Bs[lk + 1][lrow + 64] = b1.y; Bs[lk + 2][lrow + 64] = b1.z; Bs[lk + 3][lrow + 64] = b1.w;
    __syncthreads();
#pragma unroll
    for (int kk = 0; kk < 16; ++kk) {
      const float4 av0 = *(const float4*)&As[kk][ty * 8];
      const float4 av1 = *(const float4*)&As[kk][ty * 8 + 4];
      const float4 bv0 = *(const float4*)&Bs[kk][tx * 8];
      const float4 bv1 = *(const float4*)&Bs[kk][tx * 8 + 4];
      const float a[8] = {av0.x, av0.y, av0.z, av0.w, av1.x, av1.y, av1.z, av1.w};
      const float b[8] = {bv0.x, bv0.y, bv0.z, bv0.w, bv1.x, bv1.y, bv1.z, bv1.w};
#pragma unroll
      for (int i = 0; i < 8; ++i)
#pragma unroll
        for (int j = 0; j < 8; ++j)
          c[i][j] = fmaf(a[i], b[j], c[i][j]);
    }
  }

  const int n_base = bx * 128 + tx * 8;
  float bj[8];
#pragma unroll
  for (int j = 0; j < 8; ++j) bj[j] = bias ? bias[n_base + j] : 0.f;

#pragma unroll
  for (int i = 0; i < 8; ++i) {
    const int m = by * 128 + ty * 8 + i;
    float o[8];
#pragma unroll
    for (int j = 0; j < 8; ++j) {
      float v = c[i][j] + bj[j];
      if (relu) v = fmaxf(v, 0.f);
      o[j] = v;
    }
    float* dst;
    if (outk >= 0) {
      const int t = m >> 6, b = m & 63;
      dst = C + (((size_t)(t * KWIN + outk) * BBATCH + b) * NENC) + n_base;
    } else {
      dst = C + (size_t)m * Ncols + n_base;
    }
    *(float4*)dst = make_float4(o[0], o[1], o[2], o[3]);
    *(float4*)(dst + 4) = make_float4(o[4], o[5], o[6], o[7]);
  }
}

// gi_table[a][c] = emb[a,:] @ w_ih_c[c,:] + b_ih_c[c]   (18 x 768)
__global__ void gitab_kernel(const float* __restrict__ emb, const float* __restrict__ w_ih_c,
                             const float* __restrict__ b_ih_c, float* __restrict__ gt)
{
  const int idx = blockIdx.x * blockDim.x + threadIdx.x;
  if (idx >= 18 * G3) return;
  const int a = idx / G3, cgate = idx % G3;
  float s = b_ih_c[cgate];
#pragma unroll
  for (int e = 0; e < 32; ++e) s = fmaf(emb[a * 32 + e], w_ih_c[cgate * 32 + e], s);
  gt[idx] = s;
}

// Sequential GRU scan: one block per batch sample, 232 steps, stores bts for t>=40.
__global__ __launch_bounds__(256) void scan_kernel(
    const float* __restrict__ gi_all, const float* __restrict__ w_hh,
    const float* __restrict__ b_hh, float* __restrict__ bts)
{
  const int b = blockIdx.x;
  const int j = threadIdx.x;
  __shared__ float hs[256];
  hs[j] = 0.f;
  __syncthreads();

  const float* wr = w_hh + (size_t)j * 256;
  const float* wz = w_hh + (size_t)(256 + j) * 256;
  const float* wn = w_hh + (size_t)(512 + j) * 256;
  const float bhr = b_hh[j], bhz = b_hh[256 + j], bhn = b_hh[512 + j];

  for (int t = 0; t < NSTEPS; ++t) {
    const float* gi = gi_all + ((size_t)t * BBATCH + b) * G3;
    float accr = bhr, accz = bhz, accn = bhn;
#pragma unroll 8
    for (int k2 = 0; k2 < 256; k2 += 4) {
      const float4 h4 = *(const float4*)&hs[k2];
      const float4 w1 = *(const float4*)(wr + k2);
      const float4 w2 = *(const float4*)(wz + k2);
      const float4 w3 = *(const float4*)(wn + k2);
      accr = fmaf(w1.x, h4.x, accr); accr = fmaf(w1.y, h4.y, accr);
      accr = fmaf(w1.z, h4.z, accr); accr = fmaf(w1.w, h4.w, accr);
      accz = fmaf(w2.x, h4.x, accz); accz = fmaf(w2.y, h4.y, accz);
      accz = fmaf(w2.z, h4.z, accz); accz = fmaf(w2.w, h4.w, accz);
      accn = fmaf(w3.x, h4.x, accn); accn = fmaf(w3.y, h4.y, accn);
      accn = fmaf(w3.z, h4.z, accn); accn = fmaf(w3.w, h4.w, accn);
    }
    const float gr = gi[j], gz = gi[256 + j], gn = gi[512 + j];
    const float r = sigmf(gr + accr);
    const float z = sigmf(gz + accz);
    const float n = tanhf(gn + r * accn);
    const float hold = hs[j];
    const float hn = (1.f - z) * n + z * hold;
    __syncthreads();
    hs[j] = hn;
    if (t >= WRMC) bts[(((size_t)(t - WRMC)) * BBATCH + b) * MHID + j] = hn;
    __syncthreads();
  }
}

// Open-loop gate combine: h' from gi_table lookup + gh GEMM result.
__global__ __launch_bounds__(256) void open_gates(
    const float* __restrict__ gtab, const int* __restrict__ act_seq,
    const float* __restrict__ gh, const float* __restrict__ hin,
    float* __restrict__ hout, int kstep)
{
  const int row = blockIdx.x;       // 0..12287
  const int j = threadIdx.x;        // 0..255
  const int t = row >> 6, b = row & 63;
  const int a = act_seq[(WRMC + t + kstep) * BBATCH + b];
  const float* gi = gtab + a * G3;
  const float gr = gi[j], gz = gi[256 + j], gn = gi[512 + j];
  const size_t g0 = (size_t)row * G3;
  const float hr = gh[g0 + j], hz = gh[g0 + 256 + j], hnn = gh[g0 + 512 + j];
  const float h = hin[(size_t)row * MHID + j];
  const float r = sigmf(gr + hr);
  const float z = sigmf(gz + hz);
  const float n = tanhf(gn + r * hnn);
  hout[(size_t)row * MHID + j] = (1.f - z) * n + z * h;
}

extern "C" void kernel_launch(void* const* d_in, const int* in_sizes, int n_in,
                              void* d_out, int out_size, void* d_ws, size_t ws_size,
                              hipStream_t stream) {
  const float* obs    = (const float*)d_in[0];
  const int*   act    = (const int*)  d_in[1];
  const float* w_enc  = (const float*)d_in[2];
  const float* b_enc  = (const float*)d_in[3];
  const float* w_ih   = (const float*)d_in[4];
  const float* w_hh   = (const float*)d_in[5];
  const float* b_ih   = (const float*)d_in[6];
  const float* b_hh   = (const float*)d_in[7];
  const float* w_ih_c = (const float*)d_in[8];
  const float* w_hh_c = (const float*)d_in[9];
  const float* b_ih_c = (const float*)d_in[10];
  const float* b_hh_c = (const float*)d_in[11];
  const float* W1     = (const float*)d_in[12];
  const float* b1     = (const float*)d_in[13];
  const float* W2     = (const float*)d_in[14];
  const float* b2     = (const float*)d_in[15];
  const float* emb    = (const float*)d_in[16];

  float* ws  = (float*)d_ws;
  float* out = (float*)d_out;

  float* z     = ws + OFF_Z;
  float* gi    = ws + OFF_GI;
  float* bts   = ws + OFF_BTS;
  float* gtab  = ws + OFF_GTAB;
  float* hopen = ws + OFF_HOPEN;
  float* r1    = ws + OFF_R1;
  float* gbh   = ws + OFF_GBH;

  const dim3 blk(256);

  // Phase 1: encoder + input gates for the whole sequence
  gemm_tn<<<dim3(4, 120), blk, 0, stream>>>(obs, w_enc, b_enc, z, TT * BBATCH, NENC, DDIM, 0, -1);
  gemm_tn<<<dim3(6, 120), blk, 0, stream>>>(z, w_ih, b_ih, gi, TT * BBATCH, G3, NENC, 0, -1);
  gitab_kernel<<<54, 256, 0, stream>>>(emb, w_ih_c, b_ih_c, gtab);

  // Phase 2: sequential GRU scan (warm 40 + closed 192)
  scan_kernel<<<BBATCH, 256, 0, stream>>>(gi, w_hh, b_hh, bts);

  // Phase 3: open-loop rollout, 8 steps over 12288 independent rows
  for (int k = 0; k < KWIN; ++k) {
    const float* hin = (k == 0) ? bts : hopen;
    gemm_tn<<<dim3(6, 96), blk, 0, stream>>>(hin, w_hh_c, b_hh_c, gbh, RROWS, G3, MHID, 0, -1);
    open_gates<<<RROWS, 256, 0, stream>>>(gtab, act, gbh, hin, hopen, k);
    gemm_tn<<<dim3(2, 96), blk, 0, stream>>>(hopen, W1, b1, r1, RROWS, MHID, MHID, 1, -1);
    gemm_tn<<<dim3(4, 96), blk, 0, stream>>>(r1, W2, b2, out, RROWS, NENC, MHID, 0, k);
  }
}

// Round 2
// 4628.113 us; speedup vs baseline: 1.7989x; 1.7989x over previous
//
#include <hip/hip_runtime.h>
#include <math.h>

// Problem constants
#define TT   240
#define BBATCH 64
#define DDIM 7056
#define NENC 512
#define MHID 256
#define G3   768
#define WRMC 40
#define KWIN 8
#define TOUTC 192
#define RROWS (TOUTC*BBATCH)   // 12288
#define NSTEPS (WRMC + TOUTC)  // 232

// ws layout (float offsets)
#define OFF_GI    ((size_t)0)                        // 240*64*768 = 11796480
#define OFF_Z     ((size_t)11796480)                 // 7864320 (phase 1 only)
#define OFF_HOPEN OFF_Z                              // 3145728 (reuse after scan)
#define OFF_R1    (OFF_Z + (size_t)3145728)          // 3145728
#define OFF_WT    (OFF_Z + (size_t)6291456)          // 196608 (inside z region, after gi gemm)
#define OFF_BTS   (OFF_Z + (size_t)7864320)          // 3276800
#define OFF_GTAB  (OFF_BTS + (size_t)3276800)        // 13824
#define OFF_GBH   OFF_GI                             // reuse gi space for open gh

__device__ __forceinline__ float sigmf(float x) { return 1.0f / (1.0f + expf(-x)); }

// C[M,N] = A[M,K] @ W[N,K]^T + bias (optional relu, optional strided out scatter)
// Tiles: 128x128, BK=16, 256 threads, 8x8 per thread.
__global__ __launch_bounds__(256) void gemm_tn(
    const float* __restrict__ A, const float* __restrict__ W,
    const float* __restrict__ bias, float* __restrict__ C,
    int Mrows, int Ncols, int Kdim, int relu, int outk)
{
  __shared__ float As[16][132];
  __shared__ float Bs[16][132];
  const int tid = threadIdx.x;
  const int bx = blockIdx.x, by = blockIdx.y;
  const int tx = tid & 15, ty = tid >> 4;
  const int lrow = tid >> 2;
  const int lk = (tid & 3) << 2;

  const float* Ab = A + (size_t)by * 128 * Kdim;
  const float* Wb = W + (size_t)bx * 128 * Kdim;

  float c[8][8];
#pragma unroll
  for (int i = 0; i < 8; ++i)
#pragma unroll
    for (int j = 0; j < 8; ++j) c[i][j] = 0.f;

  for (int k0 = 0; k0 < Kdim; k0 += 16) {
    const float4 a0 = *(const float4*)(Ab + (size_t)lrow * Kdim + k0 + lk);
    const float4 a1 = *(const float4*)(Ab + (size_t)(lrow + 64) * Kdim + k0 + lk);
    const float4 b0 = *(const float4*)(Wb + (size_t)lrow * Kdim + k0 + lk);
    const float4 b1 = *(const float4*)(Wb + (size_t)(lrow + 64) * Kdim + k0 + lk);
    __syncthreads();
    As[lk + 0][lrow] = a0.x; As[lk + 1][lrow] = a0.y; As[lk + 2][lrow] = a0.z; As[lk + 3][lrow] = a0.w;
    As[lk + 0][lrow + 64] = a1.x; As[lk + 1][lrow + 64] = a1.y; As[lk + 2][lrow + 64] = a1.z; As[lk + 3][lrow + 64] = a1.w;
    Bs[lk + 0][lrow] = b0.x; Bs[lk + 1][lrow] = b0.y; Bs[lk + 2][lrow] = b0.z; Bs[lk + 3][lrow] = b0.w;
    Bs[lk + 0][lrow + 64] = b1.x; Bs[lk + 1][lrow + 64] = b1.y; Bs[lk + 2][lrow + 64] = b1.z; Bs[lk + 3][lrow + 64] = b1.w;
    __syncthreads();
#pragma unroll
    for (int kk = 0; kk < 16; ++kk) {
      const float4 av0 = *(const float4*)&As[kk][ty * 8];
      const float4 av1 = *(const float4*)&As[kk][ty * 8 + 4];
      const float4 bv0 = *(const float4*)&Bs[kk][tx * 8];
      const float4 bv1 = *(const float4*)&Bs[kk][tx * 8 + 4];
      const float a[8] = {av0.x, av0.y, av0.z, av0.w, av1.x, av1.y, av1.z, av1.w};
      const float b[8] = {bv0.x, bv0.y, bv0.z, bv0.w, bv1.x, bv1.y, bv1.z, bv1.w};
#pragma unroll
      for (int i = 0; i < 8; ++i)
#pragma unroll
        for (int j = 0; j < 8; ++j)
          c[i][j] = fmaf(a[i], b[j], c[i][j]);
    }
  }

  const int n_base = bx * 128 + tx * 8;
  float bj[8];
#pragma unroll
  for (int j = 0; j < 8; ++j) bj[j] = bias ? bias[n_base + j] : 0.f;

#pragma unroll
  for (int i = 0; i < 8; ++i) {
    const int m = by * 128 + ty * 8 + i;
    float o[8];
#pragma unroll
    for (int j = 0; j < 8; ++j) {
      float v = c[i][j] + bj[j];
      if (relu) v = fmaxf(v, 0.f);
      o[j] = v;
    }
    float* dst;
    if (outk >= 0) {
      const int t = m >> 6, b = m & 63;
      dst = C + (((size_t)(t * KWIN + outk) * BBATCH + b) * NENC) + n_base;
    } else {
      dst = C + (size_t)m * Ncols + n_base;
    }
    *(float4*)dst = make_float4(o[0], o[1], o[2], o[3]);
    *(float4*)(dst + 4) = make_float4(o[4], o[5], o[6], o[7]);
  }
}

// gi_table[a][c] = emb[a,:] @ w_ih_c[c,:] + b_ih_c[c]   (18 x 768)
__global__ void gitab_kernel(const float* __restrict__ emb, const float* __restrict__ w_ih_c,
                             const float* __restrict__ b_ih_c, float* __restrict__ gt)
{
  const int idx = blockIdx.x * blockDim.x + threadIdx.x;
  if (idx >= 18 * G3) return;
  const int a = idx / G3, cgate = idx % G3;
  float s = b_ih_c[cgate];
#pragma unroll
  for (int e = 0; e < 32; ++e) s = fmaf(emb[a * 32 + e], w_ih_c[cgate * 32 + e], s);
  gt[idx] = s;
}

// wt[k][j] = w_hh[j][k]  (k-major transpose, 256 x 768)
__global__ void transpose_whh(const float* __restrict__ w, float* __restrict__ wt) {
  const int id = blockIdx.x * 256 + threadIdx.x;  // 0..196607
  const int k = id / G3, j = id % G3;
  wt[id] = w[(size_t)j * MHID + k];
}

// Sequential GRU scan v2: one block per sample, 768 threads (one per gate-output),
// coalesced k-major weight loads, h broadcast from LDS.
__global__ __launch_bounds__(768) void scan2_kernel(
    const float* __restrict__ gi_all, const float* __restrict__ wt,
    const float* __restrict__ b_hh, float* __restrict__ bts)
{
  const int b = blockIdx.x;
  const int j = threadIdx.x;       // 0..767
  __shared__ float hs[256];
  __shared__ float gacc[768];
  if (j < 256) hs[j] = 0.f;
  const float bj = b_hh[j];
  __syncthreads();

  for (int t = 0; t < NSTEPS; ++t) {
    const float* gi = gi_all + ((size_t)t * BBATCH + b) * G3;
    float gr = 0.f, gz = 0.f, gn = 0.f;
    if (j < 256) { gr = gi[j]; gz = gi[256 + j]; gn = gi[512 + j]; }
    float a0 = bj, a1 = 0.f, a2 = 0.f, a3 = 0.f;
    const float* w = wt + j;
#pragma unroll 8
    for (int k0 = 0; k0 < 256; k0 += 4) {
      const float4 h4 = *(const float4*)&hs[k0];
      a0 = fmaf(w[(size_t)(k0 + 0) * G3], h4.x, a0);
      a1 = fmaf(w[(size_t)(k0 + 1) * G3], h4.y, a1);
      a2 = fmaf(w[(size_t)(k0 + 2) * G3], h4.z, a2);
      a3 = fmaf(w[(size_t)(k0 + 3) * G3], h4.w, a3);
    }
    gacc[j] = (a0 + a1) + (a2 + a3);
    __syncthreads();
    if (j < 256) {
      const float r = sigmf(gr + gacc[j]);
      const float z = sigmf(gz + gacc[256 + j]);
      const float n = tanhf(gn + r * gacc[512 + j]);
      const float hn = (1.f - z) * n + z * hs[j];
      hs[j] = hn;
      if (t >= WRMC) bts[(((size_t)(t - WRMC)) * BBATCH + b) * MHID + j] = hn;
    }
    __syncthreads();
  }
}

// Open-loop gate combine: h' from gi_table lookup + gh GEMM result.
__global__ __launch_bounds__(256) void open_gates(
    const float* __restrict__ gtab, const int* __restrict__ act_seq,
    const float* __restrict__ gh, const float* __restrict__ hin,
    float* __restrict__ hout, int kstep)
{
  const int row = blockIdx.x;       // 0..12287
  const int j = threadIdx.x;        // 0..255
  const int t = row >> 6, b = row & 63;
  const int a = act_seq[(WRMC + t + kstep) * BBATCH + b];
  const float* gi = gtab + a * G3;
  const float gr = gi[j], gz = gi[256 + j], gn = gi[512 + j];
  const size_t g0 = (size_t)row * G3;
  const float hr = gh[g0 + j], hz = gh[g0 + 256 + j], hnn = gh[g0 + 512 + j];
  const float h = hin[(size_t)row * MHID + j];
  const float r = sigmf(gr + hr);
  const float z = sigmf(gz + hz);
  const float n = tanhf(gn + r * hnn);
  hout[(size_t)row * MHID + j] = (1.f - z) * n + z * h;
}

extern "C" void kernel_launch(void* const* d_in, const int* in_sizes, int n_in,
                              void* d_out, int out_size, void* d_ws, size_t ws_size,
                              hipStream_t stream) {
  const float* obs    = (const float*)d_in[0];
  const int*   act    = (const int*)  d_in[1];
  const float* w_enc  = (const float*)d_in[2];
  const float* b_enc  = (const float*)d_in[3];
  const float* w_ih   = (const float*)d_in[4];
  const float* w_hh   = (const float*)d_in[5];
  const float* b_ih   = (const float*)d_in[6];
  const float* b_hh   = (const float*)d_in[7];
  const float* w_ih_c = (const float*)d_in[8];
  const float* w_hh_c = (const float*)d_in[9];
  const float* b_ih_c = (const float*)d_in[10];
  const float* b_hh_c = (const float*)d_in[11];
  const float* W1     = (const float*)d_in[12];
  const float* b1     = (const float*)d_in[13];
  const float* W2     = (const float*)d_in[14];
  const float* b2     = (const float*)d_in[15];
  const float* emb    = (const float*)d_in[16];

  float* ws  = (float*)d_ws;
  float* out = (float*)d_out;

  float* z     = ws + OFF_Z;
  float* gi    = ws + OFF_GI;
  float* bts   = ws + OFF_BTS;
  float* gtab  = ws + OFF_GTAB;
  float* hopen = ws + OFF_HOPEN;
  float* r1    = ws + OFF_R1;
  float* wt    = ws + OFF_WT;
  float* gbh   = ws + OFF_GBH;

  const dim3 blk(256);

  // Phase 1: encoder + input gates for the whole sequence
  gemm_tn<<<dim3(4, 120), blk, 0, stream>>>(obs, w_enc, b_enc, z, TT * BBATCH, NENC, DDIM, 0, -1);
  gemm_tn<<<dim3(6, 120), blk, 0, stream>>>(z, w_ih, b_ih, gi, TT * BBATCH, G3, NENC, 0, -1);
  transpose_whh<<<768, 256, 0, stream>>>(w_hh, wt);
  gitab_kernel<<<54, 256, 0, stream>>>(emb, w_ih_c, b_ih_c, gtab);

  // Phase 2: sequential GRU scan (warm 40 + closed 192), coalesced weights
  scan2_kernel<<<BBATCH, 768, 0, stream>>>(gi, wt, b_hh, bts);

  // Phase 3: open-loop rollout, 8 steps over 12288 independent rows
  for (int k = 0; k < KWIN; ++k) {
    const float* hin = (k == 0) ? bts : hopen;
    gemm_tn<<<dim3(6, 96), blk, 0, stream>>>(hin, w_hh_c, b_hh_c, gbh, RROWS, G3, MHID, 0, -1);
    open_gates<<<RROWS, 256, 0, stream>>>(gtab, act, gbh, hin, hopen, k);
    gemm_tn<<<dim3(2, 96), blk, 0, stream>>>(hopen, W1, b1, r1, RROWS, MHID, MHID, 1, -1);
    gemm_tn<<<dim3(4, 96), blk, 0, stream>>>(r1, W2, b2, out, RROWS, NENC, MHID, 0, k);
  }
}